// Round 11
// baseline (193.015 us; speedup 1.0000x reference)
//
#include <hip/hip_runtime.h>
#include <hip/hip_bf16.h>
#include <stdint.h>

typedef short short8 __attribute__((ext_vector_type(8)));
typedef float f32x4 __attribute__((ext_vector_type(4)));
typedef float f32x16 __attribute__((ext_vector_type(16)));
typedef __hip_bfloat16 bf16;

#define NBATCH 8
#define TSEQ   4096
#define CDIM   1024
#define HDIM   128
#define QK_SCALE 0.08838834764831845f   // 1/sqrt(128)
#define LOG2E    1.4426950408889634f

// attn schedule (R7/R10 decomposition, in PAIR units): 32 chunks of 128 q per
// batch; chunk c has P=c+1 kv-PAIRS (128 kv each); n(c)=ceil((c+1)/11) splits
// (window <= 11 pairs = 22 tiles). 63 items/batch -> 504 blocks, ONE
// generation at 2 blocks/CU.
// NOTE: __launch_bounds__ 2nd arg acted as min BLOCKS/CU here (R6). Avoid.
#define NITEMS_PB 63
static __device__ __host__ __forceinline__ int nsplits(int c) {
  return (c + 11) / 11;
}

// ---- helpers -------------------------------------------------------------
static __device__ __forceinline__ uint32_t cvt_pk_bf16(float lo, float hi) {
  uint32_t r;
  asm("v_cvt_pk_bf16_f32 %0, %1, %2" : "=v"(r) : "v"(lo), "v"(hi));
  return r;
}
static __device__ __forceinline__ short8 pack_bf16x8(float4 a, float4 b) {
  union { short8 v; uint32_t u[4]; } r;
  r.u[0] = cvt_pk_bf16(a.x, a.y);
  r.u[1] = cvt_pk_bf16(a.z, a.w);
  r.u[2] = cvt_pk_bf16(b.x, b.y);
  r.u[3] = cvt_pk_bf16(b.z, b.w);
  return r.v;
}
static __device__ __forceinline__ f32x4 mfma16(short8 a, short8 b, f32x4 c) {
  return __builtin_amdgcn_mfma_f32_16x16x32_bf16(a, b, c, 0, 0, 0);
}
static __device__ __forceinline__ f32x16 mfma32(short8 a, short8 b, f32x16 c) {
  return __builtin_amdgcn_mfma_f32_32x32x16_bf16(a, b, c, 0, 0, 0);
}
// proj barrier: lgkm drain (ds_write completion), vmcnt free-running
#define BAR() do {                                          \
    asm volatile("s_waitcnt lgkmcnt(0)" ::: "memory");      \
    __builtin_amdgcn_s_barrier();                           \
    __builtin_amdgcn_sched_barrier(0);                      \
  } while (0)
// attn barrier: vmcnt drain (global_load_lds DMA completion; has a full
// pair-interval of slack so this is not a stall), no ds_writes to drain.
#define BARV() do {                                         \
    asm volatile("s_waitcnt vmcnt(0)" ::: "memory");        \
    __builtin_amdgcn_s_barrier();                           \
    __builtin_amdgcn_sched_barrier(0);                      \
  } while (0)

// ---- prep: W -> bf16 cast + rope cos/sin table ----------------------------
__global__ void prep_kernel(const float* __restrict__ Wq,
                            const float* __restrict__ Wk,
                            const float* __restrict__ Wv,
                            bf16* __restrict__ W3,
                            float2* __restrict__ cs) {
  int idx = blockIdx.x * 256 + threadIdx.x;
  if (idx < 3 * HDIM * CDIM) {
    int which = idx >> 17;
    int off   = idx & 131071;
    const float* s = (which == 0) ? Wq : (which == 1) ? Wk : Wv;
    W3[idx] = __float2bfloat16(s[off]);
  }
  if (idx < TSEQ * 64) {
    int t = idx >> 6, i = idx & 63;
    float freq = powf(10000.0f, -(float)i * (1.0f / 64.0f));
    float ang  = (float)t * freq;
    cs[idx] = make_float2(cosf(ang), sinf(ang));
  }
}

// ---- projection: unchanged from R7/R10 (LDS-staged x, depth-2 prefetch) ----
__global__ __launch_bounds__(512) void proj_kernel(
    const float* __restrict__ x, const bf16* __restrict__ W3,
    const float2* __restrict__ cs, bf16* __restrict__ qbuf,
    bf16* __restrict__ kbuf, bf16* __restrict__ vt) {
  __shared__ __align__(16) char xlds[2][8192];
  const int tid = threadIdx.x, lane = tid & 63, wid = tid >> 6;
  const int qt = lane & 15, g = lane >> 4;
  const int row0 = blockIdx.x * 64;
  const int swz = (qt & 7) << 4;

  const int srow = tid >> 3;
  const int sbyte = srow * 128 + (((tid & 7) * 16) ^ ((srow & 7) << 4));
  const float* xsrc = x + (size_t)(row0 + srow) * CDIM + (tid & 7) * 8;

  const int cf0 = wid * 3;
  const bf16* wr0 = W3 + (size_t)(cf0 * 16 + qt) * CDIM + g * 8;
  const bf16* wr1 = wr0 + (size_t)16 * CDIM;
  const bf16* wr2 = wr0 + (size_t)32 * CDIM;

  f32x4 acc[3][4];
#pragma unroll
  for (int j = 0; j < 3; ++j)
#pragma unroll
    for (int ti = 0; ti < 4; ++ti) acc[j][ti] = (f32x4){0.f, 0.f, 0.f, 0.f};

  {
    float4 c0 = *(const float4*)(xsrc), c1 = *(const float4*)(xsrc + 4);
    *(short8*)(&xlds[0][sbyte]) = pack_bf16x8(c0, c1);
  }
  float4 xr[2][2];
  xr[1][0] = *(const float4*)(xsrc + 64);
  xr[1][1] = *(const float4*)(xsrc + 68);
  xr[0][0] = *(const float4*)(xsrc + 128);
  xr[0][1] = *(const float4*)(xsrc + 132);
  short8 wbuf[2][3];
#pragma unroll
  for (int ii = 0; ii < 2; ++ii) {
    wbuf[ii][0] = *(const short8*)(wr0 + ii * 32);
    wbuf[ii][1] = *(const short8*)(wr1 + ii * 32);
    wbuf[ii][2] = *(const short8*)(wr2 + ii * 32);
  }
  BAR();

#pragma unroll
  for (int i = 0; i < 32; ++i) {
    const int s = i >> 1, ks = i & 1;
    const char* xb = xlds[s & 1];
    short8 xa[4];
#pragma unroll
    for (int ti = 0; ti < 4; ++ti)
      xa[ti] = *(const short8*)(xb + (ti * 16 + qt) * 128 + ((ks * 64 + g * 16) ^ swz));
    const short8 w0 = wbuf[i & 1][0];
    const short8 w1 = wbuf[i & 1][1];
    const short8 w2 = wbuf[i & 1][2];
#pragma unroll
    for (int ti = 0; ti < 4; ++ti) {
      acc[0][ti] = (cf0 + 0 < 16) ? mfma16(xa[ti], w0, acc[0][ti]) : mfma16(w0, xa[ti], acc[0][ti]);
      acc[1][ti] = (cf0 + 1 < 16) ? mfma16(xa[ti], w1, acc[1][ti]) : mfma16(w1, xa[ti], acc[1][ti]);
      acc[2][ti] = (cf0 + 2 < 16) ? mfma16(xa[ti], w2, acc[2][ti]) : mfma16(w2, xa[ti], acc[2][ti]);
    }
    const int ki = i + 2;
    const int ko2 = (ki < 32) ? ki * 32 : 0;
    wbuf[i & 1][0] = *(const short8*)(wr0 + ko2);
    wbuf[i & 1][1] = *(const short8*)(wr1 + ko2);
    wbuf[i & 1][2] = *(const short8*)(wr2 + ko2);
    if (ks == 1) {
      if (s < 15)
        *(short8*)(&xlds[(s + 1) & 1][sbyte]) =
            pack_bf16x8(xr[(s + 1) & 1][0], xr[(s + 1) & 1][1]);
      if (s < 13) {
        xr[(s + 1) & 1][0] = *(const float4*)(xsrc + (s + 3) * 64);
        xr[(s + 1) & 1][1] = *(const float4*)(xsrc + (s + 3) * 64 + 4);
      }
      BAR();
    }
  }

#pragma unroll
  for (int j = 0; j < 3; ++j) {
    const int cf = cf0 + j;
    if (cf < 16) {
      const int n = cf >> 3;
      const int h = (cf & 7) * 16 + qt;
      bf16* dst = n ? kbuf : qbuf;
      const float qmul = n ? 1.0f : (QK_SCALE * LOG2E);
      const float sgn = (h & 1) ? 1.0f : -1.0f;
#pragma unroll
      for (int ti = 0; ti < 4; ++ti)
#pragma unroll
        for (int rr = 0; rr < 4; ++rr) {
          const int grow = row0 + ti * 16 + g * 4 + rr;
          const int trow = grow & (TSEQ - 1);
          const float v = acc[j][ti][rr];
          const float prt = __shfl_xor(v, 1);
          const float2 c_s = cs[trow * 64 + (h >> 1)];
          dst[(size_t)grow * HDIM + h] =
              __float2bfloat16((v * c_s.x + prt * c_s.y * sgn) * qmul);
        }
    } else {
#pragma unroll
      for (int ti = 0; ti < 4; ++ti)
#pragma unroll
        for (int rr = 0; rr < 4; ++rr) {
          const int h = (cf & 7) * 16 + g * 4 + rr;
          const int grow = row0 + ti * 16 + qt;
          vt[(size_t)(grow >> 12) * (HDIM * TSEQ) + (size_t)h * TSEQ + (grow & (TSEQ - 1))] =
              __float2bfloat16(acc[j][ti][rr]);
        }
    }
  }
}

// ---- attention: 32x32 MFMA, K via global_load_lds DMA, V direct from L2 ----
// grid 504 x 256thr (4 waves). Pair-unit R7 schedule. Wave = 32 q.
// K pair (128 kv x 128 d bf16 = 32KB) double-buffered in LDS; staged by DMA
// (global_load_lds width=16) with the XOR swizzle applied on the GLOBAL
// source address (m173 pattern); LDS dest linear. QK/softmax/repack/PV per
// 64-kv tile exactly as R10 (verified), except V fragments load straight
// from global vt (L2-resident, XCD-pinned) instead of LDS.
__global__ __launch_bounds__(256) void attn_kernel(
    const bf16* __restrict__ qbuf, const bf16* __restrict__ kbuf,
    const bf16* __restrict__ vt, bf16* __restrict__ part,
    float2* __restrict__ ml) {
  __shared__ __align__(16) char lds[2][32768];
  const int tid = threadIdx.x, lane = tid & 63, wid = tid >> 6;
  const int q32 = lane & 31, hi = lane >> 5;
  const int bid = blockIdx.x;
  const int b = bid & 7;                 // batch -> XCD pin
  // decode item (bid>>3) -> (chunk c, split jj), heavy-first (c=31 first)
  int c = 31, jj = bid >> 3, n;
  while (jj >= (n = nsplits(c))) { jj -= n; --c; }
  const int P = c + 1;                   // kv-pairs in chunk
  const int base = P / n, r = P % n;
  const int p0 = jj * base + min(jj, r);
  const int plen = base + (jj < r ? 1 : 0);
  const int qminw = c * 128 + wid * 32;
  const int swzr = (q32 & 7) << 4;

  const bf16* kbb = kbuf + (size_t)b * TSEQ * HDIM;
  const bf16* vbb = vt + (size_t)b * HDIM * TSEQ;

  // K-pair DMA: stage pair pp (kv [pp*128, pp*128+128)) into lds[bi].
  // LDS[row][bcol] <- K[pp*128+row][bcol ^ ((row&7)<<4)]  (read-side XOR
  // swizzle pre-applied to source; LDS write is linear: base + lane*16).
  auto stage_k = [&](int pp, int bi) {
    const size_t kvb = (size_t)pp * 128;
#pragma unroll
    for (int i = 0; i < 8; ++i) {
      const int o = i * 4096 + wid * 1024 + (lane << 4);
      const int row = o >> 8;
      const int bcol = o & 255;
      const uint32_t* src = (const uint32_t*)((const char*)kbb +
          (kvb + row) * 256 + (bcol ^ ((row & 7) << 4)));
      uint32_t* dst = (uint32_t*)(&lds[bi][i * 4096 + wid * 1024]);
      __builtin_amdgcn_global_load_lds(src, dst, 16, 0, 0);
    }
  };

  // Q frags: lane row q = qminw + q32; slice ks: d = ks*16 + hi*8 .. +7
  short8 qf[8];
#pragma unroll
  for (int ks = 0; ks < 8; ++ks)
    qf[ks] = *(const short8*)(qbuf +
        (size_t)(b * TSEQ + qminw + q32) * HDIM + ks * 16 + hi * 8);

  f32x16 acc[4];
#pragma unroll
  for (int dt = 0; dt < 4; ++dt)
#pragma unroll
    for (int rr = 0; rr < 16; ++rr) acc[dt][rr] = 0.f;
  float m = -3.0e38f, l = 0.f;

  // one 64-kv tile (R10-verified math; V from global)
  auto tile_compute = [&](int pp, int ta, int bi) {
    const int kv0 = pp * 128 + ta * 64;
    if (kv0 > qminw + 31) return;        // fully masked for this wave
    const char* Kl = lds[bi] + ta * 16384;
    // V frags dt 0..1 issued before QK (latency cover = QK+mask+max)
    short8 vfa[8];
#pragma unroll
    for (int d = 0; d < 2; ++d)
#pragma unroll
      for (int s = 0; s < 4; ++s)
        vfa[d * 4 + s] = *(const short8*)(vbb +
            (size_t)(d * 32 + q32) * TSEQ + kv0 + s * 16 + hi * 8);
    // ---- QK^T: A = K rows (kv), B = Q cols (q)
    f32x16 s0, s1;
#pragma unroll
    for (int rr = 0; rr < 16; ++rr) { s0[rr] = 0.f; s1[rr] = 0.f; }
#pragma unroll
    for (int ks = 0; ks < 8; ++ks) {
      const int colb = (ks * 32 + hi * 16) ^ swzr;
      const short8 kf0 = *(const short8*)(Kl + q32 * 256 + colb);
      const short8 kf1 = *(const short8*)(Kl + (32 + q32) * 256 + colb);
      s0 = mfma32(kf0, qf[ks], s0);
      s1 = mfma32(kf1, qf[ks], s1);
    }
    // V frags dt 2..3 issued here (cover = softmax)
    short8 vfb[8];
#pragma unroll
    for (int d = 0; d < 2; ++d)
#pragma unroll
      for (int s = 0; s < 4; ++s)
        vfb[d * 4 + s] = *(const short8*)(vbb +
            (size_t)((d + 2) * 32 + q32) * TSEQ + kv0 + s * 16 + hi * 8);
    // ---- causal mask (diagonal-straddling tiles only)
    if (kv0 + 63 > qminw) {
      const int q = qminw + q32;
#pragma unroll
      for (int rr = 0; rr < 16; ++rr) {
        const int kvr = (rr & 3) + 8 * (rr >> 2) + 4 * hi;
        if (kv0 + kvr > q)      s0[rr] = -1.0e30f;
        if (kv0 + 32 + kvr > q) s1[rr] = -1.0e30f;
      }
    }
    // ---- row max: 31 fmax + 1 shfl_xor cross-half reduce
    float tmax = fmaxf(s0[0], s1[0]);
#pragma unroll
    for (int rr = 1; rr < 16; ++rr)
      tmax = fmaxf(tmax, fmaxf(s0[rr], s1[rr]));
    tmax = fmaxf(tmax, __shfl_xor(tmax, 32));
    if (__any(tmax > m + 8.0f)) {        // defer-max (T13)
      const float mn = fmaxf(m, tmax);
      const float f = exp2f(m - mn);
      l *= f;
#pragma unroll
      for (int dt = 0; dt < 4; ++dt)
#pragma unroll
        for (int rr = 0; rr < 16; ++rr) acc[dt][rr] *= f;
      m = mn;
    }
    // ---- exp2 (scale*log2e folded into q); 4 partial sums
    float pa = 0.f, pb = 0.f, pc = 0.f, pd = 0.f;
#pragma unroll
    for (int rr = 0; rr < 16; ++rr) {
      const float e0 = exp2f(s0[rr] - m);
      const float e1 = exp2f(s1[rr] - m);
      s0[rr] = e0; s1[rr] = e1;
      if (rr & 1) { pb += e0; pd += e1; }
      else        { pa += e0; pc += e1; }
    }
    l += (pa + pb) + (pc + pd);
    // ---- P repack -> 4 B-frags (slice s: kv 16s..16s+15; slot k=hi*8+j)
    short8 pf[4];
    {
      uint32_t W[8], Wx[8];
#pragma unroll
      for (int w = 0; w < 8; ++w)
        W[w] = cvt_pk_bf16(s0[w * 2], s0[w * 2 + 1]);
#pragma unroll
      for (int w = 0; w < 8; ++w)
        Wx[w] = (uint32_t)__shfl_xor((int)W[w], 32);
#pragma unroll
      for (int sp = 0; sp < 2; ++sp) {
        union { short8 v; uint32_t u[4]; } pu;
        pu.u[0] = hi ? Wx[sp * 4 + 2] : W[sp * 4 + 0];
        pu.u[1] = hi ? Wx[sp * 4 + 3] : W[sp * 4 + 1];
        pu.u[2] = hi ? W[sp * 4 + 2]  : Wx[sp * 4 + 0];
        pu.u[3] = hi ? W[sp * 4 + 3]  : Wx[sp * 4 + 1];
        pf[sp] = pu.v;
      }
#pragma unroll
      for (int w = 0; w < 8; ++w)
        W[w] = cvt_pk_bf16(s1[w * 2], s1[w * 2 + 1]);
#pragma unroll
      for (int w = 0; w < 8; ++w)
        Wx[w] = (uint32_t)__shfl_xor((int)W[w], 32);
#pragma unroll
      for (int sp = 0; sp < 2; ++sp) {
        union { short8 v; uint32_t u[4]; } pu;
        pu.u[0] = hi ? Wx[sp * 4 + 2] : W[sp * 4 + 0];
        pu.u[1] = hi ? Wx[sp * 4 + 3] : W[sp * 4 + 1];
        pu.u[2] = hi ? W[sp * 4 + 2]  : Wx[sp * 4 + 0];
        pu.u[3] = hi ? W[sp * 4 + 3]  : Wx[sp * 4 + 1];
        pf[2 + sp] = pu.v;
      }
    }
    // ---- PV: acc[dt] += V^T-frag (d rows, global) x P-frag
#pragma unroll
    for (int dt = 0; dt < 4; ++dt)
#pragma unroll
      for (int s = 0; s < 4; ++s) {
        const short8 vf = (dt < 2) ? vfa[dt * 4 + s] : vfb[(dt - 2) * 4 + s];
        acc[dt] = mfma32(vf, pf[s], acc[dt]);
      }
  };

  stage_k(p0, 0);
  BARV();

  for (int p = 0; p < plen; ++p) {
    const int pp = p0 + p;
    if (p + 1 < plen) stage_k(pp + 1, (p + 1) & 1);  // DMA, full interval of slack
    tile_compute(pp, 0, p & 1);
    tile_compute(pp, 1, p & 1);
    BARV();
  }

  // ---- finalize: pair-sum l, store own-normalized bf16 partial + (m,l)
  l += __shfl_xor(l, 32);
  const float inv = l > 0.f ? 1.0f / l : 0.f;
  const int row = wid * 32 + q32;        // row within 128-q chunk
  bf16* prow = part + (size_t)bid * 16384 + (size_t)row * 128;
#pragma unroll
  for (int dt = 0; dt < 4; ++dt)
#pragma unroll
    for (int p = 0; p < 8; ++p) {
      const int d = dt * 32 + 2 * (p & 1) + 8 * (p >> 1) + 4 * hi;
      *(uint32_t*)(prow + d) =
          cvt_pk_bf16(acc[dt][2 * p] * inv, acc[dt][2 * p + 1] * inv);
    }
  if (hi == 0) ml[(size_t)bid * 128 + row] = make_float2(m, l);
}

// ---- combine splits -> final f32 output (unchanged) ------------------------
__global__ __launch_bounds__(256) void combine_kernel(
    float* __restrict__ outp, const bf16* __restrict__ part,
    const float2* __restrict__ ml) {
  const int blk = blockIdx.x;
  const int b = blk & 7, c = blk >> 3;
  int j0 = 0;
  for (int cc = 31; cc > c; --cc) j0 += nsplits(cc);
  const int ns = nsplits(c);             // 1..3
  const int t = threadIdx.x;
  const int row = t >> 1, dh = (t & 1) << 6;

  float w[3] = {0.f, 0.f, 0.f};
  float mstar = -3.0e38f;
#pragma unroll
  for (int s = 0; s < 3; ++s)
    if (s < ns) {
      const float2 v = ml[(size_t)((j0 + s) * 8 + b) * 128 + row];
      mstar = fmaxf(mstar, v.x);
    }
  float wsum = 0.f;
#pragma unroll
  for (int s = 0; s < 3; ++s)
    if (s < ns) {
      const float2 v = ml[(size_t)((j0 + s) * 8 + b) * 128 + row];
      w[s] = exp2f(v.x - mstar) * v.y;
      wsum += w[s];
    }
  const float inv = wsum > 0.f ? 1.0f / wsum : 0.f;
#pragma unroll
  for (int s = 0; s < 3; ++s) w[s] *= inv;

  float* orow = outp + (size_t)(b * TSEQ + c * 128 + row) * HDIM + dh;
#pragma unroll
  for (int jjj = 0; jjj < 64; jjj += 8) {
    float rsum[8] = {0.f, 0.f, 0.f, 0.f, 0.f, 0.f, 0.f, 0.f};
#pragma unroll
    for (int s = 0; s < 3; ++s)
      if (s < ns) {
        const short8 pv = *(const short8*)(part +
            (size_t)((j0 + s) * 8 + b) * 16384 + (size_t)row * 128 + dh + jjj);
#pragma unroll
        for (int e = 0; e < 8; ++e) {
          union { uint32_t u; float f; } cv;
          cv.u = ((uint32_t)(uint16_t)pv[e]) << 16;
          rsum[e] += w[s] * cv.f;
        }
      }
    *(float4*)(orow + jjj) = make_float4(rsum[0], rsum[1], rsum[2], rsum[3]);
    *(float4*)(orow + jjj + 4) = make_float4(rsum[4], rsum[5], rsum[6], rsum[7]);
  }
}

// ---- launch ----------------------------------------------------------------
extern "C" void kernel_launch(void* const* d_in, const int* in_sizes, int n_in,
                              void* d_out, int out_size, void* d_ws, size_t ws_size,
                              hipStream_t stream) {
  (void)in_sizes; (void)n_in; (void)out_size; (void)ws_size;
  const float* x  = (const float*)d_in[0];
  const float* Wq = (const float*)d_in[1];
  const float* Wk = (const float*)d_in[2];
  const float* Wv = (const float*)d_in[3];
  float* out = (float*)d_out;

  // ws (~45 MiB): cs@0 (2M) | W3@2M (1M) | q@3M (8M) | k@11M (8M)
  //   | vt@19M (8M) | ml@27M (0.5M) | part@28M (16.5M: 504*32KB)
  char* ws = (char*)d_ws;
  float2* cs   = (float2*)(ws);
  bf16*   W3   = (bf16*)(ws + (2u  << 20));
  bf16*   qbuf = (bf16*)(ws + (3u  << 20));
  bf16*   kbuf = (bf16*)(ws + (11u << 20));
  bf16*   vt   = (bf16*)(ws + (19u << 20));
  float2* ml   = (float2*)(ws + (27u << 20));
  bf16*   part = (bf16*)(ws + (28u << 20));

  hipLaunchKernelGGL(prep_kernel, dim3(1536), dim3(256), 0, stream, Wq, Wk, Wv, W3, cs);
  hipLaunchKernelGGL(proj_kernel, dim3(512), dim3(512), 0, stream, x, W3, cs, qbuf, kbuf, vt);
  hipLaunchKernelGGL(attn_kernel, dim3(NITEMS_PB * 8), dim3(256), 0, stream,
                     qbuf, kbuf, vt, part, ml);
  hipLaunchKernelGGL(combine_kernel, dim3(256), dim3(256), 0, stream, out, part, ml);
}

// Round 12
// 148.411 us; speedup vs baseline: 1.3005x; 1.3005x over previous
//
#include <hip/hip_runtime.h>
#include <hip/hip_bf16.h>
#include <stdint.h>

typedef short short8 __attribute__((ext_vector_type(8)));
typedef float f32x4 __attribute__((ext_vector_type(4)));
typedef float f32x16 __attribute__((ext_vector_type(16)));
typedef __hip_bfloat16 bf16;

#define NBATCH 8
#define TSEQ   4096
#define CDIM   1024
#define HDIM   128
#define QK_SCALE 0.08838834764831845f   // 1/sqrt(128)
#define LOG2E    1.4426950408889634f

// attn schedule R12: 16 chunks of 256 q per batch; chunk c has T=4(c+1)
// kv-tiles of 64; n(c)=ceil(T/22) splits. Sum_c n(c) = 32 items/batch ->
// grid = 256 blocks of 8 waves: ONE generation GUARANTEED at 1 block/CU
// (hypothesis: 64KB-LDS blocks were 1/CU resident -> 504 blocks ran as 2
// sequential generations; occupancy counters R3-R11 all ~40-50% of model).
#define NITEMS_PB 32
static __device__ __host__ __forceinline__ int nsplits(int c) {
  return (4 * (c + 1) + 21) / 22;
}

// ---- helpers -------------------------------------------------------------
static __device__ __forceinline__ uint32_t cvt_pk_bf16(float lo, float hi) {
  uint32_t r;
  asm("v_cvt_pk_bf16_f32 %0, %1, %2" : "=v"(r) : "v"(lo), "v"(hi));
  return r;
}
static __device__ __forceinline__ short8 pack_bf16x8(float4 a, float4 b) {
  union { short8 v; uint32_t u[4]; } r;
  r.u[0] = cvt_pk_bf16(a.x, a.y);
  r.u[1] = cvt_pk_bf16(a.z, a.w);
  r.u[2] = cvt_pk_bf16(b.x, b.y);
  r.u[3] = cvt_pk_bf16(b.z, b.w);
  return r.v;
}
static __device__ __forceinline__ f32x4 mfma16(short8 a, short8 b, f32x4 c) {
  return __builtin_amdgcn_mfma_f32_16x16x32_bf16(a, b, c, 0, 0, 0);
}
static __device__ __forceinline__ f32x16 mfma32(short8 a, short8 b, f32x16 c) {
  return __builtin_amdgcn_mfma_f32_32x32x16_bf16(a, b, c, 0, 0, 0);
}
// raw barrier: lgkm drained (ds_write completion), vmcnt free-running
#define BAR() do {                                          \
    asm volatile("s_waitcnt lgkmcnt(0)" ::: "memory");      \
    __builtin_amdgcn_s_barrier();                           \
    __builtin_amdgcn_sched_barrier(0);                      \
  } while (0)

// ---- prep: W -> bf16 cast + rope cos/sin table ----------------------------
__global__ void prep_kernel(const float* __restrict__ Wq,
                            const float* __restrict__ Wk,
                            const float* __restrict__ Wv,
                            bf16* __restrict__ W3,
                            float2* __restrict__ cs) {
  int idx = blockIdx.x * 256 + threadIdx.x;
  if (idx < 3 * HDIM * CDIM) {
    int which = idx >> 17;
    int off   = idx & 131071;
    const float* s = (which == 0) ? Wq : (which == 1) ? Wk : Wv;
    W3[idx] = __float2bfloat16(s[off]);
  }
  if (idx < TSEQ * 64) {
    int t = idx >> 6, i = idx & 63;
    float freq = powf(10000.0f, -(float)i * (1.0f / 64.0f));
    float ang  = (float)t * freq;
    cs[idx] = make_float2(cosf(ang), sinf(ang));
  }
}

// ---- projection: unchanged (LDS-staged x, depth-2 prefetch) ----------------
__global__ __launch_bounds__(512) void proj_kernel(
    const float* __restrict__ x, const bf16* __restrict__ W3,
    const float2* __restrict__ cs, bf16* __restrict__ qbuf,
    bf16* __restrict__ kbuf, bf16* __restrict__ vt) {
  __shared__ __align__(16) char xlds[2][8192];
  const int tid = threadIdx.x, lane = tid & 63, wid = tid >> 6;
  const int qt = lane & 15, g = lane >> 4;
  const int row0 = blockIdx.x * 64;
  const int swz = (qt & 7) << 4;

  const int srow = tid >> 3;
  const int sbyte = srow * 128 + (((tid & 7) * 16) ^ ((srow & 7) << 4));
  const float* xsrc = x + (size_t)(row0 + srow) * CDIM + (tid & 7) * 8;

  const int cf0 = wid * 3;
  const bf16* wr0 = W3 + (size_t)(cf0 * 16 + qt) * CDIM + g * 8;
  const bf16* wr1 = wr0 + (size_t)16 * CDIM;
  const bf16* wr2 = wr0 + (size_t)32 * CDIM;

  f32x4 acc[3][4];
#pragma unroll
  for (int j = 0; j < 3; ++j)
#pragma unroll
    for (int ti = 0; ti < 4; ++ti) acc[j][ti] = (f32x4){0.f, 0.f, 0.f, 0.f};

  {
    float4 c0 = *(const float4*)(xsrc), c1 = *(const float4*)(xsrc + 4);
    *(short8*)(&xlds[0][sbyte]) = pack_bf16x8(c0, c1);
  }
  float4 xr[2][2];
  xr[1][0] = *(const float4*)(xsrc + 64);
  xr[1][1] = *(const float4*)(xsrc + 68);
  xr[0][0] = *(const float4*)(xsrc + 128);
  xr[0][1] = *(const float4*)(xsrc + 132);
  short8 wbuf[2][3];
#pragma unroll
  for (int ii = 0; ii < 2; ++ii) {
    wbuf[ii][0] = *(const short8*)(wr0 + ii * 32);
    wbuf[ii][1] = *(const short8*)(wr1 + ii * 32);
    wbuf[ii][2] = *(const short8*)(wr2 + ii * 32);
  }
  BAR();

#pragma unroll
  for (int i = 0; i < 32; ++i) {
    const int s = i >> 1, ks = i & 1;
    const char* xb = xlds[s & 1];
    short8 xa[4];
#pragma unroll
    for (int ti = 0; ti < 4; ++ti)
      xa[ti] = *(const short8*)(xb + (ti * 16 + qt) * 128 + ((ks * 64 + g * 16) ^ swz));
    const short8 w0 = wbuf[i & 1][0];
    const short8 w1 = wbuf[i & 1][1];
    const short8 w2 = wbuf[i & 1][2];
#pragma unroll
    for (int ti = 0; ti < 4; ++ti) {
      acc[0][ti] = (cf0 + 0 < 16) ? mfma16(xa[ti], w0, acc[0][ti]) : mfma16(w0, xa[ti], acc[0][ti]);
      acc[1][ti] = (cf0 + 1 < 16) ? mfma16(xa[ti], w1, acc[1][ti]) : mfma16(w1, xa[ti], acc[1][ti]);
      acc[2][ti] = (cf0 + 2 < 16) ? mfma16(xa[ti], w2, acc[2][ti]) : mfma16(w2, xa[ti], acc[2][ti]);
    }
    const int ki = i + 2;
    const int ko2 = (ki < 32) ? ki * 32 : 0;
    wbuf[i & 1][0] = *(const short8*)(wr0 + ko2);
    wbuf[i & 1][1] = *(const short8*)(wr1 + ko2);
    wbuf[i & 1][2] = *(const short8*)(wr2 + ko2);
    if (ks == 1) {
      if (s < 15)
        *(short8*)(&xlds[(s + 1) & 1][sbyte]) =
            pack_bf16x8(xr[(s + 1) & 1][0], xr[(s + 1) & 1][1]);
      if (s < 13) {
        xr[(s + 1) & 1][0] = *(const float4*)(xsrc + (s + 3) * 64);
        xr[(s + 1) & 1][1] = *(const float4*)(xsrc + (s + 3) * 64 + 4);
      }
      BAR();
    }
  }

#pragma unroll
  for (int j = 0; j < 3; ++j) {
    const int cf = cf0 + j;
    if (cf < 16) {
      const int n = cf >> 3;
      const int h = (cf & 7) * 16 + qt;
      bf16* dst = n ? kbuf : qbuf;
      const float qmul = n ? 1.0f : (QK_SCALE * LOG2E);
      const float sgn = (h & 1) ? 1.0f : -1.0f;
#pragma unroll
      for (int ti = 0; ti < 4; ++ti)
#pragma unroll
        for (int rr = 0; rr < 4; ++rr) {
          const int grow = row0 + ti * 16 + g * 4 + rr;
          const int trow = grow & (TSEQ - 1);
          const float v = acc[j][ti][rr];
          const float prt = __shfl_xor(v, 1);
          const float2 c_s = cs[trow * 64 + (h >> 1)];
          dst[(size_t)grow * HDIM + h] =
              __float2bfloat16((v * c_s.x + prt * c_s.y * sgn) * qmul);
        }
    } else {
#pragma unroll
      for (int ti = 0; ti < 4; ++ti)
#pragma unroll
        for (int rr = 0; rr < 4; ++rr) {
          const int h = (cf & 7) * 16 + g * 4 + rr;
          const int grow = row0 + ti * 16 + qt;
          vt[(size_t)(grow >> 12) * (HDIM * TSEQ) + (size_t)h * TSEQ + (grow & (TSEQ - 1))] =
              __float2bfloat16(acc[j][ti][rr]);
        }
    }
  }
}

// ---- attention: R10 inner loop, 8-wave 256-q blocks, grid=256 --------------
// Block = 512 thr (8 waves), wave wid owns q rows [c*256+wid*32, +32).
// K tile [64][256B swz] @0 + V^T tile [128][128B swz] @16384 per buffer,
// double-buffered (64KB). Reg-staged (R10-verified). Inner 64-kv tile math
// identical to R10 (verified): 32x32 MFMA, per-lane q-row softmax,
// shfl_xor(32)-based P repack.
struct Stage { short8 v[4]; };

static __device__ __forceinline__ void stage_load(Stage& s, const bf16* kbb,
                                                  const bf16* vbb, int kv0,
                                                  int tid) {
#pragma unroll
  for (int i = 0; i < 2; ++i) {   // K: row = (tid>>4) + i*32, col = (tid&15)*8
    const int row = (tid >> 4) + i * 32;
    s.v[i] = *(const short8*)(kbb + (size_t)(kv0 + row) * HDIM + (tid & 15) * 8);
  }
#pragma unroll
  for (int i = 0; i < 2; ++i) {   // V^T: row(d) = (tid>>3) + i*64, col = (tid&7)*8
    const int row = (tid >> 3) + i * 64;
    s.v[2 + i] = *(const short8*)(vbb + (size_t)row * TSEQ + kv0 + (tid & 7) * 8);
  }
}
static __device__ __forceinline__ void stage_write(const Stage& s, char* buf,
                                                   int tid) {
#pragma unroll
  for (int i = 0; i < 2; ++i) {
    const int row = (tid >> 4) + i * 32;
    *(short8*)(buf + row * 256 + (((tid & 15) * 16) ^ ((row & 7) << 4))) = s.v[i];
  }
#pragma unroll
  for (int i = 0; i < 2; ++i) {
    const int row = (tid >> 3) + i * 64;
    *(short8*)(buf + 16384 + row * 128 + (((tid & 7) * 16) ^ ((row & 7) << 4))) = s.v[2 + i];
  }
}

__global__ __launch_bounds__(512) void attn_kernel(
    const bf16* __restrict__ qbuf, const bf16* __restrict__ kbuf,
    const bf16* __restrict__ vt, bf16* __restrict__ part,
    float2* __restrict__ ml) {
  __shared__ __align__(16) char lds[2][32768];
  const int tid = threadIdx.x, lane = tid & 63, wid = tid >> 6;
  const int q32 = lane & 31, hi = lane >> 5;
  const int bid = blockIdx.x;
  const int b = bid & 7;                 // batch -> XCD pin
  // decode item (bid>>3) -> (chunk c, split jj), heavy-first (c=15 first)
  int c = 15, jj = bid >> 3, n;
  while (jj >= (n = nsplits(c))) { jj -= n; --c; }
  const int T = 4 * (c + 1);             // 64-kv tiles in chunk
  const int base = T / n, r = T % n;
  const int tile0 = jj * base + min(jj, r);
  const int len = base + (jj < r ? 1 : 0);
  const int qminw = c * 256 + wid * 32;
  const int swzr = (q32 & 7) << 4;

  const bf16* kbb = kbuf + (size_t)b * TSEQ * HDIM;
  const bf16* vbb = vt + (size_t)b * HDIM * TSEQ;

  // Q frags: lane row q = qminw + q32; slice ks: d = ks*16 + hi*8 .. +7
  short8 qf[8];
#pragma unroll
  for (int ks = 0; ks < 8; ++ks)
    qf[ks] = *(const short8*)(qbuf +
        (size_t)(b * TSEQ + qminw + q32) * HDIM + ks * 16 + hi * 8);

  f32x16 acc[4];
#pragma unroll
  for (int dt = 0; dt < 4; ++dt)
#pragma unroll
    for (int rr = 0; rr < 16; ++rr) acc[dt][rr] = 0.f;
  float m = -3.0e38f, l = 0.f;

  Stage st;
  stage_load(st, kbb, vbb, tile0 * 64, tid);
  stage_write(st, lds[0], tid);
  BAR();

  for (int t = 0; t < len; ++t) {
    const int kv0 = (tile0 + t) * 64;
    const bool hn = (t + 1 < len);
    if (hn) stage_load(st, kbb, vbb, kv0 + 64, tid);  // in flight over compute

    if (kv0 <= qminw + 31) {             // skip fully-masked tiles (wave level)
      const char* Kl = lds[t & 1];
      const char* Vl = Kl + 16384;
      // ---- QK^T: A = K rows (kv), B = Q cols (q)
      f32x16 s0, s1;
#pragma unroll
      for (int rr = 0; rr < 16; ++rr) { s0[rr] = 0.f; s1[rr] = 0.f; }
#pragma unroll
      for (int ks = 0; ks < 8; ++ks) {
        const int colb = (ks * 32 + hi * 16) ^ swzr;
        const short8 kf0 = *(const short8*)(Kl + q32 * 256 + colb);
        const short8 kf1 = *(const short8*)(Kl + (32 + q32) * 256 + colb);
        s0 = mfma32(kf0, qf[ks], s0);
        s1 = mfma32(kf1, qf[ks], s1);
      }
      // ---- causal mask (diagonal-straddling tiles only)
      if (kv0 + 63 > qminw) {
        const int q = qminw + q32;
#pragma unroll
        for (int rr = 0; rr < 16; ++rr) {
          const int kvr = (rr & 3) + 8 * (rr >> 2) + 4 * hi;
          if (kv0 + kvr > q)      s0[rr] = -1.0e30f;
          if (kv0 + 32 + kvr > q) s1[rr] = -1.0e30f;
        }
      }
      // ---- row max: 31 fmax + 1 shfl_xor cross-half reduce
      float tmax = fmaxf(s0[0], s1[0]);
#pragma unroll
      for (int rr = 1; rr < 16; ++rr)
        tmax = fmaxf(tmax, fmaxf(s0[rr], s1[rr]));
      tmax = fmaxf(tmax, __shfl_xor(tmax, 32));
      if (__any(tmax > m + 8.0f)) {      // defer-max (T13)
        const float mn = fmaxf(m, tmax);
        const float f = exp2f(m - mn);
        l *= f;
#pragma unroll
        for (int dt = 0; dt < 4; ++dt)
#pragma unroll
          for (int rr = 0; rr < 16; ++rr) acc[dt][rr] *= f;
        m = mn;
      }
      // ---- exp2 (scale*log2e folded into q); 4 partial sums
      float pa = 0.f, pb = 0.f, pc = 0.f, pd = 0.f;
#pragma unroll
      for (int rr = 0; rr < 16; ++rr) {
        const float e0 = exp2f(s0[rr] - m);
        const float e1 = exp2f(s1[rr] - m);
        s0[rr] = e0; s1[rr] = e1;
        if (rr & 1) { pb += e0; pd += e1; }
        else        { pa += e0; pc += e1; }
      }
      l += (pa + pb) + (pc + pd);
      // ---- P repack -> 4 B-frags (slice s: kv 16s..16s+15; slot k=hi*8+j)
      short8 pf[4];
      {
        uint32_t W[8], Wx[8];
#pragma unroll
        for (int w = 0; w < 8; ++w)
          W[w] = cvt_pk_bf16(s0[w * 2], s0[w * 2 + 1]);
#pragma unroll
        for (int w = 0; w < 8; ++w)
          Wx[w] = (uint32_t)__shfl_xor((int)W[w], 32);
#pragma unroll
        for (int sp = 0; sp < 2; ++sp) {
          union { short8 v; uint32_t u[4]; } pu;
          pu.u[0] = hi ? Wx[sp * 4 + 2] : W[sp * 4 + 0];
          pu.u[1] = hi ? Wx[sp * 4 + 3] : W[sp * 4 + 1];
          pu.u[2] = hi ? W[sp * 4 + 2]  : Wx[sp * 4 + 0];
          pu.u[3] = hi ? W[sp * 4 + 3]  : Wx[sp * 4 + 1];
          pf[sp] = pu.v;
        }
#pragma unroll
        for (int w = 0; w < 8; ++w)
          W[w] = cvt_pk_bf16(s1[w * 2], s1[w * 2 + 1]);
#pragma unroll
        for (int w = 0; w < 8; ++w)
          Wx[w] = (uint32_t)__shfl_xor((int)W[w], 32);
#pragma unroll
        for (int sp = 0; sp < 2; ++sp) {
          union { short8 v; uint32_t u[4]; } pu;
          pu.u[0] = hi ? Wx[sp * 4 + 2] : W[sp * 4 + 0];
          pu.u[1] = hi ? Wx[sp * 4 + 3] : W[sp * 4 + 1];
          pu.u[2] = hi ? W[sp * 4 + 2]  : Wx[sp * 4 + 0];
          pu.u[3] = hi ? W[sp * 4 + 3]  : Wx[sp * 4 + 1];
          pf[2 + sp] = pu.v;
        }
      }
      // ---- PV: acc[dt] += V^T-frag (d rows) x P-frag
#pragma unroll
      for (int dt = 0; dt < 4; ++dt) {
        const char* vrow = Vl + (dt * 32 + q32) * 128;
#pragma unroll
        for (int s = 0; s < 4; ++s) {
          const short8 vf = *(const short8*)(vrow + ((s * 32 + hi * 16) ^ swzr));
          acc[dt] = mfma32(vf, pf[s], acc[dt]);
        }
      }
    }

    if (hn) stage_write(st, lds[(t + 1) & 1], tid);
    BAR();
  }

  // ---- finalize: pair-sum l, store own-normalized bf16 partial + (m,l)
  l += __shfl_xor(l, 32);
  const float inv = l > 0.f ? 1.0f / l : 0.f;
  const int row = wid * 32 + q32;        // row within 256-q chunk
  bf16* prow = part + (size_t)bid * 32768 + (size_t)row * 128;
#pragma unroll
  for (int dt = 0; dt < 4; ++dt)
#pragma unroll
    for (int p = 0; p < 8; ++p) {
      const int d = dt * 32 + 2 * (p & 1) + 8 * (p >> 1) + 4 * hi;
      *(uint32_t*)(prow + d) =
          cvt_pk_bf16(acc[dt][2 * p] * inv, acc[dt][2 * p + 1] * inv);
    }
  if (hi == 0) ml[(size_t)bid * 256 + row] = make_float2(m, l);
}

// ---- combine splits -> final f32 output ------------------------------------
// grid 256 (= 8b x 16c x 2 row-halves), 256 thr: row = rh*128 + (t>>1),
// d-half = (t&1)*64. ns(c) <= 3.
__global__ __launch_bounds__(256) void combine_kernel(
    float* __restrict__ outp, const bf16* __restrict__ part,
    const float2* __restrict__ ml) {
  const int blk = blockIdx.x;
  const int b = blk & 7, c = (blk >> 3) & 15, rh = blk >> 7;
  int j0 = 0;
  for (int cc = 15; cc > c; --cc) j0 += nsplits(cc);
  const int ns = nsplits(c);             // 1..3
  const int t = threadIdx.x;
  const int row = rh * 128 + (t >> 1), dh = (t & 1) << 6;

  float w[3] = {0.f, 0.f, 0.f};
  float mstar = -3.0e38f;
#pragma unroll
  for (int s = 0; s < 3; ++s)
    if (s < ns) {
      const float2 v = ml[(size_t)((j0 + s) * 8 + b) * 256 + row];
      mstar = fmaxf(mstar, v.x);
    }
  float wsum = 0.f;
#pragma unroll
  for (int s = 0; s < 3; ++s)
    if (s < ns) {
      const float2 v = ml[(size_t)((j0 + s) * 8 + b) * 256 + row];
      w[s] = exp2f(v.x - mstar) * v.y;
      wsum += w[s];
    }
  const float inv = wsum > 0.f ? 1.0f / wsum : 0.f;
#pragma unroll
  for (int s = 0; s < 3; ++s) w[s] *= inv;

  float* orow = outp + (size_t)(b * TSEQ + c * 256 + row) * HDIM + dh;
#pragma unroll
  for (int jjj = 0; jjj < 64; jjj += 8) {
    float rsum[8] = {0.f, 0.f, 0.f, 0.f, 0.f, 0.f, 0.f, 0.f};
#pragma unroll
    for (int s = 0; s < 3; ++s)
      if (s < ns) {
        const short8 pv = *(const short8*)(part +
            (size_t)((j0 + s) * 8 + b) * 32768 + (size_t)row * 128 + dh + jjj);
#pragma unroll
        for (int e = 0; e < 8; ++e) {
          union { uint32_t u; float f; } cv;
          cv.u = ((uint32_t)(uint16_t)pv[e]) << 16;
          rsum[e] += w[s] * cv.f;
        }
      }
    *(float4*)(orow + jjj) = make_float4(rsum[0], rsum[1], rsum[2], rsum[3]);
    *(float4*)(orow + jjj + 4) = make_float4(rsum[4], rsum[5], rsum[6], rsum[7]);
  }
}

// ---- launch ----------------------------------------------------------------
extern "C" void kernel_launch(void* const* d_in, const int* in_sizes, int n_in,
                              void* d_out, int out_size, void* d_ws, size_t ws_size,
                              hipStream_t stream) {
  (void)in_sizes; (void)n_in; (void)out_size; (void)ws_size;
  const float* x  = (const float*)d_in[0];
  const float* Wq = (const float*)d_in[1];
  const float* Wk = (const float*)d_in[2];
  const float* Wv = (const float*)d_in[3];
  float* out = (float*)d_out;

  // ws (~45 MiB): cs@0 (2M) | W3@2M (1M) | q@3M (8M) | k@11M (8M)
  //   | vt@19M (8M) | ml@27M (0.5M: 256*256*8B) | part@28M (16M: 256*64KB)
  char* ws = (char*)d_ws;
  float2* cs   = (float2*)(ws);
  bf16*   W3   = (bf16*)(ws + (2u  << 20));
  bf16*   qbuf = (bf16*)(ws + (3u  << 20));
  bf16*   kbuf = (bf16*)(ws + (11u << 20));
  bf16*   vt   = (bf16*)(ws + (19u << 20));
  float2* ml   = (float2*)(ws + (27u << 20));
  bf16*   part = (bf16*)(ws + (28u << 20));

  hipLaunchKernelGGL(prep_kernel, dim3(1536), dim3(256), 0, stream, Wq, Wk, Wv, W3, cs);
  hipLaunchKernelGGL(proj_kernel, dim3(512), dim3(512), 0, stream, x, W3, cs, qbuf, kbuf, vt);
  hipLaunchKernelGGL(attn_kernel, dim3(NITEMS_PB * 8), dim3(512), 0, stream,
                     qbuf, kbuf, vt, part, ml);
  hipLaunchKernelGGL(combine_kernel, dim3(256), dim3(256), 0, stream, out, part, ml);
}